// Round 1
// baseline (108.607 us; speedup 1.0000x reference)
//
#include <hip/hip_runtime.h>
#include <hip/hip_bf16.h>

// DenseGraphSimpleOpEdgeFlow: out[b,i,f] = sum_j attn[b,i,j,f]*support[b,j,f] + support[b,i,f]
//   support = inputs @ weight  (fp32)
//   attn = mask(sigmoid(op_emb' @ attn_w + attn_b)); diagonal op_emb replaced by self_op_emb,
//   adj' = adj + I; adj'==0 -> 0, adj'==1 (SKIP) -> 1, else sigmoid.
// Requires ws_size >= 64*96*128*4 = 3,145,728 bytes (support scratch).

#define B_ 64
#define N_ 96
#define F_ 128
#define D_ 48

typedef __attribute__((ext_vector_type(8))) short short8;
typedef __attribute__((ext_vector_type(4))) float f32x4;

__device__ __forceinline__ unsigned bfbits(float x) {
    union { __hip_bfloat16 h; unsigned short u; } cv;
    cv.h = __float2bfloat16(x);
    return (unsigned)cv.u;
}

// ---------------- Kernel 1: support = inputs @ weight  [6144,128]@[128,128] fp32 ----------------
__global__ __launch_bounds__(256, 4) void support_kernel(
    const float* __restrict__ inputs, const float* __restrict__ weight,
    float* __restrict__ support)
{
    __shared__ float in_lds[16 * F_];
    const int tid = threadIdx.x;
    const int row0 = blockIdx.x * 16;
    ((float4*)in_lds)[tid]       = ((const float4*)(inputs + (size_t)row0 * F_))[tid];
    ((float4*)in_lds)[tid + 256] = ((const float4*)(inputs + (size_t)row0 * F_))[tid + 256];
    __syncthreads();
    const int rl = tid >> 4, f0 = (tid & 15) * 8;
    float acc[8] = {0.f,0.f,0.f,0.f,0.f,0.f,0.f,0.f};
    #pragma unroll 4
    for (int k = 0; k < F_; ++k) {
        const float a = in_lds[rl * F_ + k];
        const float4 w0 = *(const float4*)(weight + k * F_ + f0);
        const float4 w1 = *(const float4*)(weight + k * F_ + f0 + 4);
        acc[0] += a * w0.x; acc[1] += a * w0.y; acc[2] += a * w0.z; acc[3] += a * w0.w;
        acc[4] += a * w1.x; acc[5] += a * w1.y; acc[6] += a * w1.z; acc[7] += a * w1.w;
    }
    float* o = support + (size_t)(row0 + rl) * F_ + f0;
    *(float4*)o       = make_float4(acc[0], acc[1], acc[2], acc[3]);
    *(float4*)(o + 4) = make_float4(acc[4], acc[5], acc[6], acc[7]);
}

// ---------------- Kernel 2: fused attn-GEMM + mask + weighted reduce + residual ----------------
// One block per (b,i). 4 waves; wave w owns output features f in [32w, 32w+32).
// A = op_emb[b,i,:,:] (96x48, bf16, LDS, XOR-swizzled), B = attn_w (48x128, bf16, regs).
// MFMA 16x16x32: k-slot fill d = ks*32 + (lane>>4)*8 + e, identical for A and B
// (layout-independent: A/B share the per-group k map, so any physical-k permutation cancels).
// C/D layout (HW-verified): col = lane&15, row = (lane>>4)*4 + reg.
__global__ __launch_bounds__(256, 4) void fused_kernel(
    const float* __restrict__ op_emb,
    const unsigned* __restrict__ adjw,      // raw 32-bit view of adj (int32 or int64)
    const float* __restrict__ attn_w,
    const float* __restrict__ attn_b,
    const float* __restrict__ self_op,
    const float* __restrict__ support,
    float* __restrict__ out)
{
    __shared__ __align__(16) unsigned short Atile[N_ * 64];  // 12 KB, cols 48..63 zero
    __shared__ int jcode[N_];

    const int blk  = blockIdx.x;
    const int b    = blk / N_;
    const int i    = blk - b * N_;
    const int tid  = threadIdx.x;
    const int lane = tid & 63;
    const int wv   = tid >> 6;      // wave 0..3
    const int lg   = lane >> 4;     // k-slot group 0..3
    const int lm   = lane & 15;

    const int rowbase = (b * N_ + i) * N_;  // index into [B*N*N]

    // --- adj dtype sniff: int64 little-endian has all-zero high words (values 0..4) ---
    const unsigned probe = adjw[2 * lane + 1];
    const bool use32 = __any(probe != 0);   // wave-uniform; identical across waves

    // --- B fragments (attn_w) + bias, held in registers ---
    short8 bfrag[2][2];
    float  bbias[2];
    #pragma unroll
    for (int t = 0; t < 2; ++t) {
        const int f = (2 * wv + t) * 16 + lm;
        bbias[t] = attn_b[f];
        #pragma unroll
        for (int ks = 0; ks < 2; ++ks) {
            short8 v;
            #pragma unroll
            for (int e = 0; e < 8; ++e) {
                const int d = ks * 32 + lg * 8 + e;
                v[e] = (d < D_) ? (short)bfbits(attn_w[d * F_ + f]) : (short)0;
            }
            bfrag[t][ks] = v;
        }
    }

    // --- stage A tile: fp32 global -> bf16 LDS, diagonal row replaced, XOR-swizzled ---
    for (int word = tid; word < N_ * 32; word += 256) {
        const int j = word >> 5, cw = word & 31;
        const int d = cw * 2;
        float x0 = 0.f, x1 = 0.f;
        if (d < D_) {
            if (j == i) { x0 = self_op[d]; x1 = self_op[d + 1]; }
            else {
                const float2 p = *(const float2*)(op_emb + (size_t)(rowbase + j) * D_ + d);
                x0 = p.x; x1 = p.y;
            }
        }
        const unsigned packed = bfbits(x0) | (bfbits(x1) << 16);
        const int byte = j * 128 + ((cw * 4) ^ ((j & 7) << 4));
        *(unsigned*)((char*)Atile + byte) = packed;
    }
    // --- adj codes: 0 -> zero, 1 -> skip(attn=1), 2 -> sigmoid ---
    if (tid < N_) {
        const int idx = rowbase + tid;
        int a = use32 ? (int)adjw[idx] : (int)adjw[2 * idx];
        a += (tid == i) ? 1 : 0;
        jcode[tid] = (a == 0) ? 0 : ((a == 1) ? 1 : 2);
    }
    __syncthreads();

    // --- MFMA: logits[96 x 32(per wave)] ---
    f32x4 acc[6][2];
    #pragma unroll
    for (int mt = 0; mt < 6; ++mt) {
        acc[mt][0] = (f32x4){0.f, 0.f, 0.f, 0.f};
        acc[mt][1] = (f32x4){0.f, 0.f, 0.f, 0.f};
    }
    #pragma unroll
    for (int mt = 0; mt < 6; ++mt) {
        const int j   = mt * 16 + lm;
        const int swz = (lm & 7) << 4;
        const short8 a0 = *(const short8*)((const char*)Atile + j * 128 + (( 0 + lg * 16) ^ swz));
        const short8 a1 = *(const short8*)((const char*)Atile + j * 128 + ((64 + lg * 16) ^ swz));
        acc[mt][0] = __builtin_amdgcn_mfma_f32_16x16x32_bf16(a0, bfrag[0][0], acc[mt][0], 0, 0, 0);
        acc[mt][0] = __builtin_amdgcn_mfma_f32_16x16x32_bf16(a1, bfrag[0][1], acc[mt][0], 0, 0, 0);
        acc[mt][1] = __builtin_amdgcn_mfma_f32_16x16x32_bf16(a0, bfrag[1][0], acc[mt][1], 0, 0, 0);
        acc[mt][1] = __builtin_amdgcn_mfma_f32_16x16x32_bf16(a1, bfrag[1][1], acc[mt][1], 0, 0, 0);
    }

    // --- epilogue: sigmoid + mask + weighted reduce over j ---
    float osum[2] = {0.f, 0.f};
    const float* srow = support + (size_t)b * N_ * F_;
    #pragma unroll
    for (int mt = 0; mt < 6; ++mt) {
        #pragma unroll
        for (int r = 0; r < 4; ++r) {
            const int j    = mt * 16 + lg * 4 + r;
            const int code = jcode[j];
            #pragma unroll
            for (int t = 0; t < 2; ++t) {
                const int f = (2 * wv + t) * 16 + lm;
                const float logit = acc[mt][t][r] + bbias[t];
                const float sig   = 1.f / (1.f + __expf(-logit));
                const float av    = (code == 2) ? sig : ((code == 1) ? 1.f : 0.f);
                osum[t] += av * srow[j * F_ + f];
            }
        }
    }
    // lanes {l, l+16, l+32, l+48} hold disjoint j-subsets of the same f: butterfly-reduce
    #pragma unroll
    for (int t = 0; t < 2; ++t) {
        float v = osum[t];
        v += __shfl_xor(v, 16);
        v += __shfl_xor(v, 32);
        if (lg == 0) {
            const int f = (2 * wv + t) * 16 + lm;
            out[(size_t)(b * N_ + i) * F_ + f] = v + srow[i * F_ + f];
        }
    }
}

extern "C" void kernel_launch(void* const* d_in, const int* in_sizes, int n_in,
                              void* d_out, int out_size, void* d_ws, size_t ws_size,
                              hipStream_t stream) {
    const float*    inputs  = (const float*)d_in[0];
    const unsigned* adjw    = (const unsigned*)d_in[1];
    const float*    op_emb  = (const float*)d_in[2];
    const float*    weight  = (const float*)d_in[3];
    const float*    attn_w  = (const float*)d_in[4];
    const float*    attn_b  = (const float*)d_in[5];
    const float*    self_op = (const float*)d_in[6];
    float* out     = (float*)d_out;
    float* support = (float*)d_ws;  // 6144*128 fp32 = 3,145,728 bytes

    support_kernel<<<(B_ * N_) / 16, 256, 0, stream>>>(inputs, weight, support);
    fused_kernel<<<B_ * N_, 256, 0, stream>>>(op_emb, adjw, attn_w, attn_b, self_op,
                                              support, out);
}

// Round 2
// 100.928 us; speedup vs baseline: 1.0761x; 1.0761x over previous
//
#include <hip/hip_runtime.h>
#include <hip/hip_bf16.h>

// DenseGraphSimpleOpEdgeFlow: out[b,i,f] = sum_j attn[b,i,j,f]*support[b,j,f] + support[b,i,f]
//   support = inputs @ weight  (fp32)
//   attn = mask(sigmoid(op_emb' @ attn_w + attn_b)); diagonal op_emb replaced by self_op_emb,
//   adj' = adj + I; adj'==0 -> 0, adj'==1 (SKIP) -> 1, else sigmoid.
// R2 structure: block = (b, 6 consecutive i). support fragments + attn_w fragments live in
// registers for the whole block (amortized 6x); A-tile double-buffered in LDS; per-16-j-slab
// MFMA->epilogue fusion keeps acc pressure at 8 VGPRs.
// Requires ws_size >= 64*96*128*4 = 3,145,728 bytes (support scratch).

#define B_ 64
#define N_ 96
#define F_ 128
#define D_ 48
#define G_ 6
#define NGRP (N_ / G_)   // 16 groups -> grid = 64*16 = 1024 blocks = 4/CU

typedef __attribute__((ext_vector_type(8))) short short8;
typedef __attribute__((ext_vector_type(4))) float f32x4;

__device__ __forceinline__ unsigned bfbits(float x) {
    union { __hip_bfloat16 h; unsigned short u; } cv;
    cv.h = __float2bfloat16(x);
    return (unsigned)cv.u;
}

// ---------------- Kernel 1: support = inputs @ weight  [6144,128]@[128,128] fp32 ----------------
__global__ __launch_bounds__(256, 4) void support_kernel(
    const float* __restrict__ inputs, const float* __restrict__ weight,
    float* __restrict__ support)
{
    __shared__ float in_lds[16 * F_];
    const int tid = threadIdx.x;
    const int row0 = blockIdx.x * 16;
    ((float4*)in_lds)[tid]       = ((const float4*)(inputs + (size_t)row0 * F_))[tid];
    ((float4*)in_lds)[tid + 256] = ((const float4*)(inputs + (size_t)row0 * F_))[tid + 256];
    __syncthreads();
    const int rl = tid >> 4, f0 = (tid & 15) * 8;
    float acc[8] = {0.f,0.f,0.f,0.f,0.f,0.f,0.f,0.f};
    #pragma unroll 4
    for (int k = 0; k < F_; ++k) {
        const float a = in_lds[rl * F_ + k];
        const float4 w0 = *(const float4*)(weight + k * F_ + f0);
        const float4 w1 = *(const float4*)(weight + k * F_ + f0 + 4);
        acc[0] += a * w0.x; acc[1] += a * w0.y; acc[2] += a * w0.z; acc[3] += a * w0.w;
        acc[4] += a * w1.x; acc[5] += a * w1.y; acc[6] += a * w1.z; acc[7] += a * w1.w;
    }
    float* o = support + (size_t)(row0 + rl) * F_ + f0;
    *(float4*)o       = make_float4(acc[0], acc[1], acc[2], acc[3]);
    *(float4*)(o + 4) = make_float4(acc[4], acc[5], acc[6], acc[7]);
}

// ---------------- Kernel 2: fused attn-GEMM + mask + weighted reduce + residual ----------------
// 4 waves; wave w owns output features f in [32w, 32w+32). MFMA 16x16x32 k-slot fill
// d = ks*32 + (lane>>4)*8 + e identical for A and B (k permutation cancels).
// C/D layout (HW-verified): col = lane&15 (-> f), row = (lane>>4)*4 + reg (-> j).
__global__ __launch_bounds__(256, 4) void fused_kernel(
    const float* __restrict__ op_emb,
    const unsigned* __restrict__ adjw,      // raw 32-bit view of adj (int32 or int64)
    const float* __restrict__ attn_w,
    const float* __restrict__ attn_b,
    const float* __restrict__ self_op,
    const float* __restrict__ support,
    float* __restrict__ out)
{
    __shared__ __align__(16) unsigned short Atile[2][N_ * 64];  // 2 x 12 KB, cols 48..63 zero
    __shared__ float2 jmask[2][N_];                             // x: sigmoid-mask, y: skip-add

    const int tid  = threadIdx.x;
    const int lane = tid & 63;
    const int wv   = tid >> 6;      // wave 0..3
    const int lg   = lane >> 4;     // k-slot group / j-subgroup 0..3
    const int lm   = lane & 15;

    const int blk = blockIdx.x;
    const int b   = blk / NGRP;
    const int grp = blk - b * NGRP;
    const int i0  = grp * G_;

    // --- adj dtype sniff: int64 little-endian has all-zero high words (values 0..4) ---
    const unsigned probe = adjw[2 * lane + 1];
    const bool use32 = __any(probe != 0);   // wave-uniform; identical across waves

    // --- B fragments (attn_w) + bias, registers, once per block ---
    short8 bfrag[2][2];
    float  bbias[2];
    #pragma unroll
    for (int t = 0; t < 2; ++t) {
        const int f = (2 * wv + t) * 16 + lm;
        bbias[t] = attn_b[f];
        #pragma unroll
        for (int ks = 0; ks < 2; ++ks) {
            short8 v;
            #pragma unroll
            for (int e = 0; e < 8; ++e) {
                const int d = ks * 32 + lg * 8 + e;
                v[e] = (d < D_) ? (short)bfbits(attn_w[d * F_ + f]) : (short)0;
            }
            bfrag[t][ks] = v;
        }
    }

    // --- support fragments, registers, once per block (layout matches C/D frag) ---
    const float* srow = support + (size_t)b * N_ * F_;
    float sfrag[6][4][2];
    #pragma unroll
    for (int mt = 0; mt < 6; ++mt)
        #pragma unroll
        for (int r = 0; r < 4; ++r)
            #pragma unroll
            for (int t = 0; t < 2; ++t)
                sfrag[mt][r][t] = srow[(size_t)(mt * 16 + lg * 4 + r) * F_ + (2 * wv + t) * 16 + lm];

    // --- zero the k-pad (d in [48,64)) of both buffers once ---
    for (int v = tid; v < 2 * N_ * 8; v += 256) {
        const int pb = (v >= N_ * 8) ? 1 : 0;
        const int vv = v - pb * N_ * 8;
        const int j = vv >> 3, c = vv & 7;
        const int byte = j * 128 + ((96 + c * 4) ^ ((j & 7) << 4));
        *(unsigned*)((char*)(&Atile[pb][0]) + byte) = 0u;
    }

    // --- staging: fp32 global -> bf16 LDS (XOR-swizzled), diagonal row <- self_op ---
    auto stage = [&](int i, int pb) {
        const size_t rb = (size_t)(b * N_ + i) * N_;
        const float* src = op_emb + rb * D_;
        for (int w = tid; w < N_ * 12; w += 256) {
            const int j = w / 12;
            const int c = w - j * 12;
            const int d = c * 4;
            float4 p;
            if (j == i) p = *(const float4*)(self_op + d);
            else        p = *(const float4*)(src + (size_t)j * D_ + d);
            const unsigned lo = bfbits(p.x) | (bfbits(p.y) << 16);
            const unsigned hi = bfbits(p.z) | (bfbits(p.w) << 16);
            const int byte = j * 128 + ((c * 8) ^ ((j & 7) << 4));
            *(uint2*)((char*)(&Atile[pb][0]) + byte) = make_uint2(lo, hi);
        }
        if (tid < N_) {
            const size_t idx = rb + tid;
            int a = use32 ? (int)adjw[idx] : (int)adjw[2 * idx];
            a += (tid == i) ? 1 : 0;
            jmask[pb][tid] = make_float2(a >= 2 ? 1.f : 0.f, a == 1 ? 1.f : 0.f);
        }
    };

    stage(i0, 0);
    __syncthreads();

    for (int g = 0; g < G_; ++g) {
        const int cur = g & 1;
        const int i = i0 + g;
        if (g + 1 < G_) stage(i + 1, cur ^ 1);   // overlap next-tile staging with compute

        float osum[2] = {0.f, 0.f};
        #pragma unroll
        for (int mt = 0; mt < 6; ++mt) {
            const int jr  = mt * 16 + lm;
            const int swz = (lm & 7) << 4;
            const char* base = (const char*)(&Atile[cur][0]) + jr * 128;
            const short8 a0 = *(const short8*)(base + (( 0 + lg * 16) ^ swz));
            const short8 a1 = *(const short8*)(base + ((64 + lg * 16) ^ swz));
            f32x4 acc0 = (f32x4){0.f, 0.f, 0.f, 0.f};
            f32x4 acc1 = (f32x4){0.f, 0.f, 0.f, 0.f};
            acc0 = __builtin_amdgcn_mfma_f32_16x16x32_bf16(a0, bfrag[0][0], acc0, 0, 0, 0);
            acc0 = __builtin_amdgcn_mfma_f32_16x16x32_bf16(a1, bfrag[0][1], acc0, 0, 0, 0);
            acc1 = __builtin_amdgcn_mfma_f32_16x16x32_bf16(a0, bfrag[1][0], acc1, 0, 0, 0);
            acc1 = __builtin_amdgcn_mfma_f32_16x16x32_bf16(a1, bfrag[1][1], acc1, 0, 0, 0);
            #pragma unroll
            for (int r = 0; r < 4; ++r) {
                const int j = mt * 16 + lg * 4 + r;
                const float2 m = jmask[cur][j];
                {
                    const float e   = __expf(-(acc0[r] + bbias[0]));
                    const float sig = __builtin_amdgcn_rcpf(1.f + e);
                    const float av  = __builtin_fmaf(m.x, sig, m.y);
                    osum[0] = __builtin_fmaf(av, sfrag[mt][r][0], osum[0]);
                }
                {
                    const float e   = __expf(-(acc1[r] + bbias[1]));
                    const float sig = __builtin_amdgcn_rcpf(1.f + e);
                    const float av  = __builtin_fmaf(m.x, sig, m.y);
                    osum[1] = __builtin_fmaf(av, sfrag[mt][r][1], osum[1]);
                }
            }
        }
        // lanes {l, l+16, l+32, l+48} hold disjoint j-subsets of the same f: butterfly-reduce
        #pragma unroll
        for (int t = 0; t < 2; ++t) {
            float v = osum[t];
            v += __shfl_xor(v, 16);
            v += __shfl_xor(v, 32);
            if (lg == 0) {
                const int f = (2 * wv + t) * 16 + lm;
                out[(size_t)(b * N_ + i) * F_ + f] = v + srow[(size_t)i * F_ + f];
            }
        }
        __syncthreads();
    }
}

extern "C" void kernel_launch(void* const* d_in, const int* in_sizes, int n_in,
                              void* d_out, int out_size, void* d_ws, size_t ws_size,
                              hipStream_t stream) {
    const float*    inputs  = (const float*)d_in[0];
    const unsigned* adjw    = (const unsigned*)d_in[1];
    const float*    op_emb  = (const float*)d_in[2];
    const float*    weight  = (const float*)d_in[3];
    const float*    attn_w  = (const float*)d_in[4];
    const float*    attn_b  = (const float*)d_in[5];
    const float*    self_op = (const float*)d_in[6];
    float* out     = (float*)d_out;
    float* support = (float*)d_ws;  // 6144*128 fp32 = 3,145,728 bytes

    support_kernel<<<(B_ * N_) / 16, 256, 0, stream>>>(inputs, weight, support);
    fused_kernel<<<B_ * NGRP, 256, 0, stream>>>(op_emb, adjw, attn_w, attn_b, self_op,
                                                support, out);
}

// Round 3
// 80.053 us; speedup vs baseline: 1.3567x; 1.2608x over previous
//
#include <hip/hip_runtime.h>
#include <hip/hip_bf16.h>

// DenseGraphSimpleOpEdgeFlow: out[b,i,f] = sum_j attn[b,i,j,f]*support[b,j,f] + support[b,i,f]
//   support = inputs @ weight  (fp32)
//   attn = mask(sigmoid(op_emb' @ attn_w + attn_b)); diagonal op_emb replaced by self_op_emb,
//   adj' = adj + I; adj'==0 -> 0, adj'==1 (SKIP) -> 1, else sigmoid.
// R3: fix R2's scratch spill (launch_bounds (256,2) so sfrag's 48 f32 stay in VGPRs;
// R2 showed 33 MB WRITE_SIZE of spill at VGPR cap 128). Fold bias into MFMA C-init and
// -log2(e) into the weights so sigmoid = rcp(1+exp2(acc)) -- 2 fewer VALU ops/term.
// Requires ws_size >= 64*96*128*4 = 3,145,728 bytes (support scratch).

#define B_ 64
#define N_ 96
#define F_ 128
#define D_ 48
#define G_ 6
#define NGRP (N_ / G_)   // 16 groups -> grid = 64*16 = 1024 blocks

typedef __attribute__((ext_vector_type(8))) short short8;
typedef __attribute__((ext_vector_type(4))) float f32x4;

#if __has_builtin(__builtin_amdgcn_exp2f)
#define EXP2(x) __builtin_amdgcn_exp2f(x)
#else
#define EXP2(x) exp2f(x)
#endif

__device__ __forceinline__ unsigned bfbits(float x) {
    union { __hip_bfloat16 h; unsigned short u; } cv;
    cv.h = __float2bfloat16(x);
    return (unsigned)cv.u;
}

// ---------------- Kernel 1: support = inputs @ weight  [6144,128]@[128,128] fp32 ----------------
// 96 blocks x 64 rows; 4-row register tile per thread amortizes weight reads (L2 393->96 MB).
#define SROWS 64
#define SLDS_STRIDE 132   // pad: (rl+s*16)*132+k spreads the 4 row-groups across banks
__global__ __launch_bounds__(256, 2) void support_kernel(
    const float* __restrict__ inputs, const float* __restrict__ weight,
    float* __restrict__ support)
{
    __shared__ float in_lds[SROWS * SLDS_STRIDE];   // ~33 KB
    const int tid = threadIdx.x;
    const int row0 = blockIdx.x * SROWS;
    const float4* src = (const float4*)(inputs + (size_t)row0 * F_);
    #pragma unroll
    for (int k = 0; k < 8; ++k) {
        const int idx = tid + k * 256;          // 2048 float4 words
        const int j = idx >> 5, c = idx & 31;
        *(float4*)(in_lds + j * SLDS_STRIDE + c * 4) = src[idx];
    }
    __syncthreads();
    const int rl = tid >> 4, f0 = (tid & 15) * 8;
    float acc[4][8];
    #pragma unroll
    for (int s = 0; s < 4; ++s)
        #pragma unroll
        for (int e = 0; e < 8; ++e) acc[s][e] = 0.f;
    #pragma unroll 2
    for (int k = 0; k < F_; ++k) {
        const float4 w0 = *(const float4*)(weight + k * F_ + f0);
        const float4 w1 = *(const float4*)(weight + k * F_ + f0 + 4);
        #pragma unroll
        for (int s = 0; s < 4; ++s) {
            const float a = in_lds[(rl + s * 16) * SLDS_STRIDE + k];
            acc[s][0] += a * w0.x; acc[s][1] += a * w0.y;
            acc[s][2] += a * w0.z; acc[s][3] += a * w0.w;
            acc[s][4] += a * w1.x; acc[s][5] += a * w1.y;
            acc[s][6] += a * w1.z; acc[s][7] += a * w1.w;
        }
    }
    #pragma unroll
    for (int s = 0; s < 4; ++s) {
        float* o = support + (size_t)(row0 + rl + s * 16) * F_ + f0;
        *(float4*)o       = make_float4(acc[s][0], acc[s][1], acc[s][2], acc[s][3]);
        *(float4*)(o + 4) = make_float4(acc[s][4], acc[s][5], acc[s][6], acc[s][7]);
    }
}

// ---------------- Kernel 2: fused attn-GEMM + mask + weighted reduce + residual ----------------
// 4 waves; wave w owns output features f in [32w, 32w+32). MFMA 16x16x32 k-slot fill
// d = ks*32 + (lane>>4)*8 + e identical for A and B (k permutation cancels).
// C/D layout (HW-verified): col = lane&15 (-> f), row = (lane>>4)*4 + reg (-> j).
__global__ __launch_bounds__(256, 2) void fused_kernel(
    const float* __restrict__ op_emb,
    const unsigned* __restrict__ adjw,      // raw 32-bit view of adj (int32 or int64)
    const float* __restrict__ attn_w,
    const float* __restrict__ attn_b,
    const float* __restrict__ self_op,
    const float* __restrict__ support,
    float* __restrict__ out)
{
    __shared__ __align__(16) unsigned short Atile[2][N_ * 64];  // 2 x 12 KB, cols 48..63 zero
    __shared__ float2 jmask[2][N_];                             // x: sigmoid-mask, y: skip-add

    const int tid  = threadIdx.x;
    const int lane = tid & 63;
    const int wv   = tid >> 6;      // wave 0..3
    const int lg   = lane >> 4;     // k-slot group / j-subgroup 0..3
    const int lm   = lane & 15;

    const int blk = blockIdx.x;
    const int b   = blk / NGRP;
    const int grp = blk - b * NGRP;
    const int i0  = grp * G_;

    const float kNL2E = -1.44269504088896f;   // -log2(e): exp(-x) = exp2(kNL2E*x)

    // --- adj dtype sniff: int64 little-endian has all-zero high words (values 0..4) ---
    const unsigned probe = adjw[2 * lane + 1];
    const bool use32 = __any(probe != 0);   // wave-uniform; identical across waves

    // --- B fragments (attn_w pre-scaled by -log2e) + bias, registers, once per block ---
    short8 bfrag[2][2];
    float  bbias[2];
    #pragma unroll
    for (int t = 0; t < 2; ++t) {
        const int f = (2 * wv + t) * 16 + lm;
        bbias[t] = attn_b[f] * kNL2E;
        #pragma unroll
        for (int ks = 0; ks < 2; ++ks) {
            short8 v;
            #pragma unroll
            for (int e = 0; e < 8; ++e) {
                const int d = ks * 32 + lg * 8 + e;
                v[e] = (d < D_) ? (short)bfbits(attn_w[d * F_ + f] * kNL2E) : (short)0;
            }
            bfrag[t][ks] = v;
        }
    }

    // --- support fragments, registers, once per block (layout matches C/D frag) ---
    const float* srow = support + (size_t)b * N_ * F_;
    float sfrag[6][4][2];
    #pragma unroll
    for (int mt = 0; mt < 6; ++mt)
        #pragma unroll
        for (int r = 0; r < 4; ++r)
            #pragma unroll
            for (int t = 0; t < 2; ++t)
                sfrag[mt][r][t] = srow[(size_t)(mt * 16 + lg * 4 + r) * F_ + (2 * wv + t) * 16 + lm];

    // --- zero the k-pad (d in [48,64)) of both buffers once ---
    for (int v = tid; v < 2 * N_ * 8; v += 256) {
        const int pb = (v >= N_ * 8) ? 1 : 0;
        const int vv = v - pb * N_ * 8;
        const int j = vv >> 3, c = vv & 7;
        const int byte = j * 128 + ((96 + c * 4) ^ ((j & 7) << 4));
        *(unsigned*)((char*)(&Atile[pb][0]) + byte) = 0u;
    }

    // --- staging: fp32 global -> bf16 LDS (XOR-swizzled), diagonal row <- self_op ---
    auto stage = [&](int i, int pb) {
        const size_t rb = (size_t)(b * N_ + i) * N_;
        const float* src = op_emb + rb * D_;
        for (int w = tid; w < N_ * 12; w += 256) {
            const int j = w / 12;
            const int c = w - j * 12;
            const int d = c * 4;
            float4 p;
            if (j == i) p = *(const float4*)(self_op + d);
            else        p = *(const float4*)(src + (size_t)j * D_ + d);
            const unsigned lo = bfbits(p.x) | (bfbits(p.y) << 16);
            const unsigned hi = bfbits(p.z) | (bfbits(p.w) << 16);
            const int byte = j * 128 + ((c * 8) ^ ((j & 7) << 4));
            *(uint2*)((char*)(&Atile[pb][0]) + byte) = make_uint2(lo, hi);
        }
        if (tid < N_) {
            const size_t idx = rb + tid;
            int a = use32 ? (int)adjw[idx] : (int)adjw[2 * idx];
            a += (tid == i) ? 1 : 0;
            jmask[pb][tid] = make_float2(a >= 2 ? 1.f : 0.f, a == 1 ? 1.f : 0.f);
        }
    };

    stage(i0, 0);
    __syncthreads();

    for (int g = 0; g < G_; ++g) {
        const int cur = g & 1;
        const int i = i0 + g;
        if (g + 1 < G_) stage(i + 1, cur ^ 1);   // overlap next-tile staging with compute

        float osum[2] = {0.f, 0.f};
        #pragma unroll
        for (int mt = 0; mt < 6; ++mt) {
            const int jr  = mt * 16 + lm;
            const int swz = (lm & 7) << 4;
            const char* base = (const char*)(&Atile[cur][0]) + jr * 128;
            const short8 a0 = *(const short8*)(base + (( 0 + lg * 16) ^ swz));
            const short8 a1 = *(const short8*)(base + ((64 + lg * 16) ^ swz));
            // bias pre-folded into C-init (bias depends only on f = col = lane&15)
            f32x4 acc0 = (f32x4){bbias[0], bbias[0], bbias[0], bbias[0]};
            f32x4 acc1 = (f32x4){bbias[1], bbias[1], bbias[1], bbias[1]};
            acc0 = __builtin_amdgcn_mfma_f32_16x16x32_bf16(a0, bfrag[0][0], acc0, 0, 0, 0);
            acc0 = __builtin_amdgcn_mfma_f32_16x16x32_bf16(a1, bfrag[0][1], acc0, 0, 0, 0);
            acc1 = __builtin_amdgcn_mfma_f32_16x16x32_bf16(a0, bfrag[1][0], acc1, 0, 0, 0);
            acc1 = __builtin_amdgcn_mfma_f32_16x16x32_bf16(a1, bfrag[1][1], acc1, 0, 0, 0);
            #pragma unroll
            for (int r = 0; r < 4; ++r) {
                const int j = mt * 16 + lg * 4 + r;
                const float2 m = jmask[cur][j];
                // acc = -log2e*(op_emb.attn_w + b)  ->  sigmoid = rcp(1 + exp2(acc))
                const float e0 = EXP2(acc0[r]);
                const float e1 = EXP2(acc1[r]);
                const float sig0 = __builtin_amdgcn_rcpf(1.f + e0);
                const float sig1 = __builtin_amdgcn_rcpf(1.f + e1);
                const float av0 = __builtin_fmaf(m.x, sig0, m.y);
                const float av1 = __builtin_fmaf(m.x, sig1, m.y);
                osum[0] = __builtin_fmaf(av0, sfrag[mt][r][0], osum[0]);
                osum[1] = __builtin_fmaf(av1, sfrag[mt][r][1], osum[1]);
            }
        }
        // lanes {l, l+16, l+32, l+48} hold disjoint j-subsets of the same f: butterfly-reduce
        #pragma unroll
        for (int t = 0; t < 2; ++t) {
            float v = osum[t];
            v += __shfl_xor(v, 16);
            v += __shfl_xor(v, 32);
            if (lg == 0) {
                const int f = (2 * wv + t) * 16 + lm;
                out[(size_t)(b * N_ + i) * F_ + f] = v + srow[(size_t)i * F_ + f];
            }
        }
        __syncthreads();
    }
}

extern "C" void kernel_launch(void* const* d_in, const int* in_sizes, int n_in,
                              void* d_out, int out_size, void* d_ws, size_t ws_size,
                              hipStream_t stream) {
    const float*    inputs  = (const float*)d_in[0];
    const unsigned* adjw    = (const unsigned*)d_in[1];
    const float*    op_emb  = (const float*)d_in[2];
    const float*    weight  = (const float*)d_in[3];
    const float*    attn_w  = (const float*)d_in[4];
    const float*    attn_b  = (const float*)d_in[5];
    const float*    self_op = (const float*)d_in[6];
    float* out     = (float*)d_out;
    float* support = (float*)d_ws;  // 6144*128 fp32 = 3,145,728 bytes

    support_kernel<<<(B_ * N_) / SROWS, 256, 0, stream>>>(inputs, weight, support);
    fused_kernel<<<B_ * NGRP, 256, 0, stream>>>(op_emb, adjw, attn_w, attn_b, self_op,
                                                support, out);
}

// Round 4
// 77.305 us; speedup vs baseline: 1.4049x; 1.0355x over previous
//
#include <hip/hip_runtime.h>
#include <hip/hip_bf16.h>

// DenseGraphSimpleOpEdgeFlow: out[b,i,f] = sum_j attn[b,i,j,f]*support[b,j,f] + support[b,i,f]
//   support = inputs @ weight  (fp32)
//   attn = mask(sigmoid(op_emb' @ attn_w + attn_b)); diagonal op_emb replaced by self_op_emb,
//   adj' = adj + I; adj'==0 -> 0, adj'==1 (SKIP) -> 1, else sigmoid.
// R4: T14 async-stage split -- R3 was latency-bound (VALUBusy 23%, same 89us with op_emb
// L3-resident). Loads for tile g+1 issue at iter top into regs; converts+ds_writes happen
// after compute; one barrier/iter. Diagonal handled in epilogue via per-block a_self
// (sigmoid(self_op.W+b) is (b,i)-independent), so staging is a branch-free copy.
// Requires ws_size >= 64*96*128*4 = 3,145,728 bytes (support scratch).

#define B_ 64
#define N_ 96
#define F_ 128
#define D_ 48
#define G_ 6
#define NGRP (N_ / G_)   // 16 groups -> grid = 64*16 = 1024 blocks

typedef __attribute__((ext_vector_type(8))) short short8;
typedef __attribute__((ext_vector_type(4))) float f32x4;

#if __has_builtin(__builtin_amdgcn_exp2f)
#define EXP2(x) __builtin_amdgcn_exp2f(x)
#else
#define EXP2(x) exp2f(x)
#endif

__device__ __forceinline__ unsigned bfbits(float x) {
    union { __hip_bfloat16 h; unsigned short u; } cv;
    cv.h = __float2bfloat16(x);
    return (unsigned)cv.u;
}
__device__ __forceinline__ float bf2f(unsigned short u) {
    union { float f; unsigned v; } cv;
    cv.v = ((unsigned)u) << 16;
    return cv.f;
}

// ---------------- Kernel 1: support = inputs @ weight  [6144,128]@[128,128] fp32 ----------------
// 384 blocks x 16 rows (1.5 blocks/CU); weight is L2-resident (64 KB broadcast).
__global__ __launch_bounds__(256, 4) void support_kernel(
    const float* __restrict__ inputs, const float* __restrict__ weight,
    float* __restrict__ support)
{
    __shared__ float in_lds[16 * F_];
    const int tid = threadIdx.x;
    const int row0 = blockIdx.x * 16;
    ((float4*)in_lds)[tid]       = ((const float4*)(inputs + (size_t)row0 * F_))[tid];
    ((float4*)in_lds)[tid + 256] = ((const float4*)(inputs + (size_t)row0 * F_))[tid + 256];
    __syncthreads();
    const int rl = tid >> 4, f0 = (tid & 15) * 8;
    float acc[8] = {0.f,0.f,0.f,0.f,0.f,0.f,0.f,0.f};
    #pragma unroll 4
    for (int k = 0; k < F_; ++k) {
        const float a = in_lds[rl * F_ + k];
        const float4 w0 = *(const float4*)(weight + k * F_ + f0);
        const float4 w1 = *(const float4*)(weight + k * F_ + f0 + 4);
        acc[0] += a * w0.x; acc[1] += a * w0.y; acc[2] += a * w0.z; acc[3] += a * w0.w;
        acc[4] += a * w1.x; acc[5] += a * w1.y; acc[6] += a * w1.z; acc[7] += a * w1.w;
    }
    float* o = support + (size_t)(row0 + rl) * F_ + f0;
    *(float4*)o       = make_float4(acc[0], acc[1], acc[2], acc[3]);
    *(float4*)(o + 4) = make_float4(acc[4], acc[5], acc[6], acc[7]);
}

// ---------------- Kernel 2: fused attn-GEMM + mask + weighted reduce + residual ----------------
// 4 waves; wave w owns output features f in [32w, 32w+32). MFMA 16x16x32 k-slot fill
// d = ks*32 + (lane>>4)*8 + e identical for A and B (k permutation cancels).
// C/D layout (HW-verified): col = lane&15 (-> f), row = (lane>>4)*4 + reg (-> j).
__global__ __launch_bounds__(256, 2) void fused_kernel(
    const float* __restrict__ op_emb,
    const unsigned* __restrict__ adjw,      // raw 32-bit view of adj (int32 or int64)
    const float* __restrict__ attn_w,
    const float* __restrict__ attn_b,
    const float* __restrict__ self_op,
    const float* __restrict__ support,
    float* __restrict__ out)
{
    __shared__ __align__(16) unsigned short Atile[2][N_ * 64];  // 2 x 12 KB, cols 48..63 zero
    __shared__ __align__(16) float4 jmask[2][N_];  // x: sig-mask, y: const-add, z: self-mask

    const int tid  = threadIdx.x;
    const int lane = tid & 63;
    const int wv   = tid >> 6;      // wave 0..3
    const int lg   = lane >> 4;     // k-slot group / j-subgroup 0..3
    const int lm   = lane & 15;

    const int blk = blockIdx.x;
    const int b   = blk / NGRP;
    const int grp = blk - b * NGRP;
    const int i0  = grp * G_;

    const float kNL2E = -1.44269504088896f;   // -log2(e): exp(-x) = exp2(kNL2E*x)

    // --- adj dtype sniff: int64 little-endian has all-zero high words (values 0..4) ---
    const unsigned probe = adjw[2 * lane + 1];
    const bool use32 = __any(probe != 0);   // wave-uniform; identical across waves

    // --- B fragments (attn_w pre-scaled by -log2e) + bias, registers, once per block ---
    short8 bfrag[2][2];
    float  bbias[2];
    #pragma unroll
    for (int t = 0; t < 2; ++t) {
        const int f = (2 * wv + t) * 16 + lm;
        bbias[t] = attn_b[f] * kNL2E;
        #pragma unroll
        for (int ks = 0; ks < 2; ++ks) {
            short8 v;
            #pragma unroll
            for (int e = 0; e < 8; ++e) {
                const int d = ks * 32 + lg * 8 + e;
                v[e] = (d < D_) ? (short)bfbits(attn_w[d * F_ + f] * kNL2E) : (short)0;
            }
            bfrag[t][ks] = v;
        }
    }

    // --- a_self[t] = sigmoid(self_op . attn_w[:,f] + b[f]) -- (b,i)-independent, per block ---
    float a_self[2];
    {
        float part[2] = {0.f, 0.f};
        #pragma unroll
        for (int ks = 0; ks < 2; ++ks) {
            #pragma unroll
            for (int e = 0; e < 8; ++e) {
                const int d = ks * 32 + lg * 8 + e;
                const float sv = (d < D_) ? self_op[d] : 0.f;
                part[0] = __builtin_fmaf(bf2f((unsigned short)bfrag[0][ks][e]), sv, part[0]);
                part[1] = __builtin_fmaf(bf2f((unsigned short)bfrag[1][ks][e]), sv, part[1]);
            }
        }
        #pragma unroll
        for (int t = 0; t < 2; ++t) {
            float v = part[t];
            v += __shfl_xor(v, 16);
            v += __shfl_xor(v, 32);          // sum over the 4 lg groups -> full 48-dot
            a_self[t] = __builtin_amdgcn_rcpf(1.f + EXP2(v + bbias[t]));
        }
    }

    // --- support fragments, registers, once per block (layout matches C/D frag) ---
    const float* srow = support + (size_t)b * N_ * F_;
    float sfrag[6][4][2];
    #pragma unroll
    for (int mt = 0; mt < 6; ++mt)
        #pragma unroll
        for (int r = 0; r < 4; ++r)
            #pragma unroll
            for (int t = 0; t < 2; ++t)
                sfrag[mt][r][t] = srow[(size_t)(mt * 16 + lg * 4 + r) * F_ + (2 * wv + t) * 16 + lm];

    // --- zero the k-pad (d in [48,64)) of both buffers once ---
    for (int v = tid; v < 2 * N_ * 8; v += 256) {
        const int pb = (v >= N_ * 8) ? 1 : 0;
        const int vv = v - pb * N_ * 8;
        const int j = vv >> 3, c = vv & 7;
        const int byte = j * 128 + ((96 + c * 4) ^ ((j & 7) << 4));
        *(unsigned*)((char*)(&Atile[pb][0]) + byte) = 0u;
    }

    // --- prologue: stage tile 0 + jmask 0 (latency exposed once) ---
    {
        const float* tb = op_emb + (size_t)(b * N_ + i0) * (N_ * D_);
        float4 ld[5];
        #pragma unroll
        for (int s = 0; s < 5; ++s) {
            const int w = tid + s * 256;
            if (w < N_ * 12) ld[s] = *(const float4*)(tb + 4 * w);
        }
        int araw = 0;
        if (tid < N_)
        {
            const size_t idx = (size_t)(b * N_ + i0) * N_ + tid;
            araw = use32 ? (int)adjw[idx] : (int)adjw[2 * idx];
        }
        #pragma unroll
        for (int s = 0; s < 5; ++s) {
            const int w = tid + s * 256;
            if (w < N_ * 12) {
                const int j = w / 12, c = w - 12 * j;
                const int byte = j * 128 + ((c * 8) ^ ((j & 7) << 4));
                *(uint2*)((char*)(&Atile[0][0]) + byte) =
                    make_uint2(bfbits(ld[s].x) | (bfbits(ld[s].y) << 16),
                               bfbits(ld[s].z) | (bfbits(ld[s].w) << 16));
            }
        }
        if (tid < N_) {
            float4 m;
            if (tid == i0) m = make_float4(0.f, (araw == 0) ? 1.f : 0.f, (araw == 0) ? 0.f : 1.f, 0.f);
            else           m = make_float4((araw >= 2) ? 1.f : 0.f, (araw == 1) ? 1.f : 0.f, 0.f, 0.f);
            jmask[0][tid] = m;
        }
    }
    __syncthreads();

    for (int g = 0; g < G_; ++g) {
        const int cur = g & 1;
        const int i = i0 + g;
        const bool has_next = (g + 1 < G_);

        // ---- issue next-tile global loads EARLY (results consumed after compute) ----
        float4 ld[5];
        int araw = 0;
        if (has_next) {
            const float* tb = op_emb + (size_t)(b * N_ + (i + 1)) * (N_ * D_);
            #pragma unroll
            for (int s = 0; s < 5; ++s) {
                const int w = tid + s * 256;
                if (w < N_ * 12) ld[s] = *(const float4*)(tb + 4 * w);
            }
            if (tid < N_) {
                const size_t idx = (size_t)(b * N_ + (i + 1)) * N_ + tid;
                araw = use32 ? (int)adjw[idx] : (int)adjw[2 * idx];
            }
        }

        // ---- compute on buffer cur (hides the staging-load latency) ----
        float osum[2] = {0.f, 0.f};
        #pragma unroll
        for (int mt = 0; mt < 6; ++mt) {
            const int jr  = mt * 16 + lm;
            const int swz = (lm & 7) << 4;
            const char* base = (const char*)(&Atile[cur][0]) + jr * 128;
            const short8 a0 = *(const short8*)(base + (( 0 + lg * 16) ^ swz));
            const short8 a1 = *(const short8*)(base + ((64 + lg * 16) ^ swz));
            f32x4 acc0 = (f32x4){bbias[0], bbias[0], bbias[0], bbias[0]};
            f32x4 acc1 = (f32x4){bbias[1], bbias[1], bbias[1], bbias[1]};
            acc0 = __builtin_amdgcn_mfma_f32_16x16x32_bf16(a0, bfrag[0][0], acc0, 0, 0, 0);
            acc0 = __builtin_amdgcn_mfma_f32_16x16x32_bf16(a1, bfrag[0][1], acc0, 0, 0, 0);
            acc1 = __builtin_amdgcn_mfma_f32_16x16x32_bf16(a0, bfrag[1][0], acc1, 0, 0, 0);
            acc1 = __builtin_amdgcn_mfma_f32_16x16x32_bf16(a1, bfrag[1][1], acc1, 0, 0, 0);
            #pragma unroll
            for (int r = 0; r < 4; ++r) {
                const int j = mt * 16 + lg * 4 + r;
                const float4 m = jmask[cur][j];
                const float base0 = __builtin_fmaf(m.z, a_self[0], m.y);
                const float base1 = __builtin_fmaf(m.z, a_self[1], m.y);
                // acc = -log2e*(op_emb.attn_w + b)  ->  sigmoid = rcp(1 + exp2(acc))
                const float sig0 = __builtin_amdgcn_rcpf(1.f + EXP2(acc0[r]));
                const float sig1 = __builtin_amdgcn_rcpf(1.f + EXP2(acc1[r]));
                const float av0 = __builtin_fmaf(m.x, sig0, base0);
                const float av1 = __builtin_fmaf(m.x, sig1, base1);
                osum[0] = __builtin_fmaf(av0, sfrag[mt][r][0], osum[0]);
                osum[1] = __builtin_fmaf(av1, sfrag[mt][r][1], osum[1]);
            }
        }

        // ---- output: lanes {l, l+16, l+32, l+48} hold disjoint j-subsets of same f ----
        #pragma unroll
        for (int t = 0; t < 2; ++t) {
            float v = osum[t];
            v += __shfl_xor(v, 16);
            v += __shfl_xor(v, 32);
            if (lg == 0) {
                const int f = (2 * wv + t) * 16 + lm;
                out[(size_t)(b * N_ + i) * F_ + f] = v + srow[(size_t)i * F_ + f];
            }
        }

        // ---- write next tile to LDS (loads have had the whole compute phase to land) ----
        if (has_next) {
            #pragma unroll
            for (int s = 0; s < 5; ++s) {
                const int w = tid + s * 256;
                if (w < N_ * 12) {
                    const int j = w / 12, c = w - 12 * j;
                    const int byte = j * 128 + ((c * 8) ^ ((j & 7) << 4));
                    *(uint2*)((char*)(&Atile[cur ^ 1][0]) + byte) =
                        make_uint2(bfbits(ld[s].x) | (bfbits(ld[s].y) << 16),
                                   bfbits(ld[s].z) | (bfbits(ld[s].w) << 16));
                }
            }
            if (tid < N_) {
                float4 m;
                const int in = i + 1;
                if (tid == in) m = make_float4(0.f, (araw == 0) ? 1.f : 0.f, (araw == 0) ? 0.f : 1.f, 0.f);
                else           m = make_float4((araw >= 2) ? 1.f : 0.f, (araw == 1) ? 1.f : 0.f, 0.f, 0.f);
                jmask[cur ^ 1][tid] = m;
            }
            __syncthreads();
        }
    }
}

extern "C" void kernel_launch(void* const* d_in, const int* in_sizes, int n_in,
                              void* d_out, int out_size, void* d_ws, size_t ws_size,
                              hipStream_t stream) {
    const float*    inputs  = (const float*)d_in[0];
    const unsigned* adjw    = (const unsigned*)d_in[1];
    const float*    op_emb  = (const float*)d_in[2];
    const float*    weight  = (const float*)d_in[3];
    const float*    attn_w  = (const float*)d_in[4];
    const float*    attn_b  = (const float*)d_in[5];
    const float*    self_op = (const float*)d_in[6];
    float* out     = (float*)d_out;
    float* support = (float*)d_ws;  // 6144*128 fp32 = 3,145,728 bytes

    support_kernel<<<(B_ * N_) / 16, 256, 0, stream>>>(inputs, weight, support);
    fused_kernel<<<B_ * NGRP, 256, 0, stream>>>(op_emb, adjw, attn_w, attn_b, self_op,
                                                support, out);
}